// Round 6
// baseline (655.050 us; speedup 1.0000x reference)
//
#include <hip/hip_runtime.h>
#include <hip/hip_bf16.h>

typedef __bf16 bf16x8 __attribute__((ext_vector_type(8)));
typedef float  f32x4  __attribute__((ext_vector_type(4)));
typedef unsigned short ushort;
typedef ushort ushort4v __attribute__((ext_vector_type(4)));

#if __has_builtin(__builtin_amdgcn_exp2f)
#define EXP2(x) __builtin_amdgcn_exp2f(x)
#else
#define EXP2(x) exp2f(x)
#endif

__device__ __forceinline__ ushort f2bf(float f) {
  union { float f; unsigned u; } v; v.f = f;
  unsigned r = v.u + 0x7FFFu + ((v.u >> 16) & 1u);
  return (ushort)(r >> 16);
}

typedef __attribute__((address_space(1))) const unsigned int as1_uint;
typedef __attribute__((address_space(3))) unsigned int as3_uint;
__device__ __forceinline__ void gll16(const void* g, void* l) {
  __builtin_amdgcn_global_load_lds((as1_uint*)g, (as3_uint*)l, 16, 0, 0);
}

// ------------------------------------------------ all casts + mask prep (merged)
// y 0-3: weight f32->bf16; y 4: mask; y 5-7: q/k/v f32->bf16.
// mask pre-scaled by log2(e): attn softmax runs in base-2 domain.
__global__ void prep_all(const float* __restrict__ Wq, const float* __restrict__ Wk,
                         const float* __restrict__ Wv, const float* __restrict__ Wo,
                         const float* __restrict__ q, const float* __restrict__ k,
                         const float* __restrict__ v, const int* __restrict__ mask,
                         ushort4v* __restrict__ wqb, ushort4v* __restrict__ wkb,
                         ushort4v* __restrict__ wvb, ushort4v* __restrict__ wob,
                         ushort4v* __restrict__ qb, ushort4v* __restrict__ kb,
                         ushort4v* __restrict__ vb, float* __restrict__ madd) {
  int y = blockIdx.y;
  if (y == 4) {
    int i = blockIdx.x * blockDim.x + threadIdx.x;
    if (i < 8192) {
      int mv = mask[i];
      madd[i] = (mv == 0) ? -9e15f * 1.44269504f : (float)mv * 1.44269504f;
    }
    return;
  }
  const float* s; ushort4v* d; int n4;
  if (y < 4) {
    s = (y == 0) ? Wq : (y == 1) ? Wk : (y == 2) ? Wv : Wo;
    d = (y == 0) ? wqb : (y == 1) ? wkb : (y == 2) ? wvb : wob;
    n4 = 1024 * 1024 / 4;
  } else {
    s = (y == 5) ? q : (y == 6) ? k : v;
    d = (y == 5) ? qb : (y == 6) ? kb : vb;
    n4 = 8192 * 1024 / 4;
  }
  const float4* s4p = (const float4*)s;
  for (int i = blockIdx.x * blockDim.x + threadIdx.x; i < n4; i += gridDim.x * blockDim.x) {
    float4 vv = s4p[i]; ushort4v o;
    o[0] = f2bf(vv.x); o[1] = f2bf(vv.y); o[2] = f2bf(vv.z); o[3] = f2bf(vv.w);
    d[i] = o;
  }
}

// ------------------------------------------------ GEMM core  C = A @ W^T + bias
// A [8192][1024] bf16, W [1024][1024] bf16. global_load_lds staging, pre-swizzled source.
// XCD-aware grid: blockIdx.x = M-tile (64), blockIdx.y = N-tile (8) so the 8
// N-blocks sharing one A-panel have linear bids m + 64n + 512z == m (mod 8):
// same XCD -> A-panel fetched once from HBM, 7x from that XCD's L2.
// mode 0: bf16 out in [B,H,T,D]; mode 1: f32 out [M][N]; mode 2: bf16 out transposed [B,H,D,T]
__device__ __forceinline__ void gemm_core(
    const ushort* __restrict__ A, const ushort* __restrict__ W,
    const float* __restrict__ bias, void* __restrict__ outp,
    float scale, int mode, ushort* smem)
{
  const int tid = threadIdx.x, lane = tid & 63, wid = tid >> 6;
  const int r0 = blockIdx.x * 128, c0 = blockIdx.y * 128;
  const int wr = (wid >> 1) * 64, wc = (wid & 1) * 64;
  const int K = 1024;
  ushort* sA = smem;
  ushort* sB = smem + 8192;

  f32x4 acc[4][4] = {};

  for (int kt = 0; kt < 16; ++kt) {
    const int k0 = kt * 64;
#pragma unroll
    for (int i = 0; i < 4; ++i) {
      int s = (wid * 4 + i) * 64 + lane;
      int row = s >> 3, sl = s & 7, gsl = sl ^ (row & 7);
      gll16(&A[(size_t)(r0 + row) * K + k0 + gsl * 8], &sA[(wid * 4 + i) * 512]);
      gll16(&W[(size_t)(c0 + row) * K + k0 + gsl * 8], &sB[(wid * 4 + i) * 512]);
    }
    __syncthreads();
#pragma unroll
    for (int kk = 0; kk < 2; ++kk) {
      bf16x8 af[4], bf[4];
#pragma unroll
      for (int mf = 0; mf < 4; ++mf) {
        int row = wr + mf * 16 + (lane & 15);
        int slot = (kk * 4 + (lane >> 4)) ^ (row & 7);
        af[mf] = *(const bf16x8*)&sA[row * 64 + slot * 8];
      }
#pragma unroll
      for (int nf = 0; nf < 4; ++nf) {
        int row = wc + nf * 16 + (lane & 15);
        int slot = (kk * 4 + (lane >> 4)) ^ (row & 7);
        bf[nf] = *(const bf16x8*)&sB[row * 64 + slot * 8];
      }
#pragma unroll
      for (int mf = 0; mf < 4; ++mf)
#pragma unroll
        for (int nf = 0; nf < 4; ++nf)
          acc[mf][nf] = __builtin_amdgcn_mfma_f32_16x16x32_bf16(af[mf], bf[nf], acc[mf][nf], 0, 0, 0);
    }
    __syncthreads();
  }

  if (mode == 2) {
    // transpose epilogue through LDS: sT[col][row ^ ((col&7)<<3)], 128x128
    ushort* sT = smem;
#pragma unroll
    for (int nf = 0; nf < 4; ++nf) {
      int col = wc + nf * 16 + (lane & 15);
      float bv = bias[c0 + col];
#pragma unroll
      for (int mf = 0; mf < 4; ++mf)
#pragma unroll
        for (int r = 0; r < 4; ++r) {
          int row = wr + mf * 16 + ((lane >> 4) * 4) + r;
          sT[col * 128 + (row ^ ((col & 7) << 3))] = f2bf(acc[mf][nf][r] + bv);
        }
    }
    __syncthreads();
    int bidx = r0 >> 11, tb = r0 & 2047;
#pragma unroll
    for (int it = 0; it < 8; ++it) {
      int colr = it * 16 + wid * 4 + (lane >> 4);
      int t0 = (lane & 15) * 8;
      int4 v = *(const int4*)&sT[colr * 128 + (t0 ^ ((colr & 7) << 3))];
      int colg = c0 + colr;
      int hh = colg >> 6, d = colg & 63;
      *(int4*)&((ushort*)outp)[((size_t)(bidx * 16 + hh) * 64 + d) * 2048 + tb + t0] = v;
    }
    return;
  }

#pragma unroll
  for (int nf = 0; nf < 4; ++nf) {
    int col = c0 + wc + nf * 16 + (lane & 15);
    float bv = bias[col];
#pragma unroll
    for (int mf = 0; mf < 4; ++mf) {
#pragma unroll
      for (int r = 0; r < 4; ++r) {
        int row = r0 + wr + mf * 16 + ((lane >> 4) * 4) + r;
        float v = (acc[mf][nf][r] + bv) * scale;
        if (mode == 0) {
          int b = row >> 11, t = row & 2047;
          int h = col >> 6, d = col & 63;
          ((ushort*)outp)[(((size_t)(b * 16 + h) * 2048 + t) << 6) + d] = f2bf(v);
        } else {
          ((float*)outp)[(size_t)row * 1024 + col] = v;
        }
      }
    }
  }
}

__global__ __launch_bounds__(256) void gemm3(
    const ushort* __restrict__ qb, const ushort* __restrict__ kb, const ushort* __restrict__ vb,
    const ushort* __restrict__ wq, const ushort* __restrict__ wk, const ushort* __restrict__ wv,
    const float* __restrict__ bq, const float* __restrict__ bk, const float* __restrict__ bv,
    ushort* __restrict__ Qs, ushort* __restrict__ Ks, ushort* __restrict__ Vts)
{
  __shared__ __align__(16) ushort smem[16384];
  int z = blockIdx.z;
  const ushort *A, *W; const float* bias; ushort* out; float scale; int mode;
  // Q scale carries log2(e): softmax computed as 2^x downstream.
  if (z == 0)      { A = qb; W = wq; bias = bq; out = Qs;  scale = 0.125f * 1.44269504f; mode = 0; }
  else if (z == 1) { A = kb; W = wk; bias = bk; out = Ks;  scale = 1.0f;   mode = 0; }
  else             { A = vb; W = wv; bias = bv; out = Vts; scale = 1.0f;   mode = 2; }
  gemm_core(A, W, bias, out, scale, mode, smem);
}

__global__ __launch_bounds__(256) void gemmF(
    const ushort* __restrict__ Oat, const ushort* __restrict__ wo,
    const float* __restrict__ bo, float* __restrict__ out)
{
  __shared__ __align__(16) ushort smem[16384];
  gemm_core(Oat, wo, bo, out, 1.0f, 1, smem);
}

// ------------------------------------------------ flash attention (no-LDS)
// Q,K: [B,H,2048,64] bf16 (Q pre-scaled by 0.125*log2e); Vt: [B,H,64,2048] bf16;
// O: [B,T,H,D] bf16. Base-2 softmax, mask as QK C-init, ones-MFMA psum.
// NO LDS, NO barriers: K/V fragments are read straight from global. Per head,
// K+V = 512 KB and all 32 q-tile blocks sit on one XCD's L2 (swizzle below);
// the 4 waves of a block read IDENTICAL kf/vf addresses so L1 (32KB >= 16KB
// tile working set) serves 3 of 4 waves. Address identity vs the staged
// version verified: slot XOR cancels -> kf = Kh[(n0+af*16+m)*64+kk*32+qg*8],
// vf = Vh[(af*16+m)*2048+n0+kk*32+qg*8]. Softmax arithmetic unchanged (R2).
__global__ __launch_bounds__(256) void attn(
    const ushort* __restrict__ Q, const ushort* __restrict__ Km,
    const ushort* __restrict__ Vt, const float* __restrict__ madd,
    ushort* __restrict__ O)
{
  const int tid = threadIdx.x, lane = tid & 63, wid = tid >> 6;
  const int bid = blockIdx.x;
  // XCD-aware mapping: all 32 q-tiles of one (b,h) land on one XCD's L2
  const int x = bid & 7, g = bid >> 3;
  const int pair = x * 8 + (g >> 5), qt = g & 31;
  const int b = pair >> 4, h = pair & 15;

  const size_t hb = (size_t)pair * (2048 * 64);
  const ushort* Qh = Q + hb + (size_t)qt * (64 * 64);
  const float* mb = madd + b * 2048;

  const int m = lane & 15, qg = lane >> 4;

  // per-lane fragment base pointers, advanced per k-tile
  const ushort* Kp = Km + hb + (size_t)m * 64 + qg * 8;    // +af*1024, +kk*32; tile stride 4096
  const ushort* Vp = Vt + hb + (size_t)m * 2048 + qg * 8;  // +af*32768, +kk*32; tile stride 64

  // Q fragments straight from global (16B contiguous per lane, one-time)
  bf16x8 qf[2];
#pragma unroll
  for (int kk = 0; kk < 2; ++kk)
    qf[kk] = *(const bf16x8*)&Qh[(size_t)(wid * 16 + m) * 64 + kk * 32 + qg * 8];

  // mask double-buffer: consume MC this tile, prefetch MN for next
  f32x4 mA[4], mB[4];
#pragma unroll
  for (int af = 0; af < 4; ++af)
    mA[af] = *(const f32x4*)&mb[af * 16 + qg * 4];

  union { unsigned u[4]; bf16x8 v; } onesu;
  onesu.u[0] = onesu.u[1] = onesu.u[2] = onesu.u[3] = 0x3F803F80u;
  const bf16x8 ones = onesu.v;

  float runm = -3.0e38f;
  f32x4 o[4] = {};
  f32x4 osum = {};

#define TILE_BODY(MC, MN, KT) do {                                              \
    f32x4 s4_[4];                                                               \
    _Pragma("unroll")                                                           \
    for (int af = 0; af < 4; ++af) s4_[af] = MC[af];                            \
    if ((KT) < 31) {                                                            \
      const float* ms_ = mb + ((KT) + 1) * 64 + qg * 4;                         \
      _Pragma("unroll")                                                         \
      for (int af = 0; af < 4; ++af) MN[af] = *(const f32x4*)&ms_[af * 16];     \
    }                                                                           \
    __builtin_amdgcn_s_setprio(1);                                              \
    _Pragma("unroll")                                                           \
    for (int af = 0; af < 4; ++af) {                                            \
      bf16x8 kf0_ = *(const bf16x8*)&Kp[af * 1024];                             \
      bf16x8 kf1_ = *(const bf16x8*)&Kp[af * 1024 + 32];                        \
      s4_[af] = __builtin_amdgcn_mfma_f32_16x16x32_bf16(kf0_, qf[0], s4_[af], 0, 0, 0); \
      s4_[af] = __builtin_amdgcn_mfma_f32_16x16x32_bf16(kf1_, qf[1], s4_[af], 0, 0, 0); \
    }                                                                           \
    __builtin_amdgcn_s_setprio(0);                                              \
    float tmax_ = fmaxf(fmaxf(s4_[0][0], s4_[0][1]), fmaxf(s4_[0][2], s4_[0][3])); \
    _Pragma("unroll")                                                           \
    for (int af = 1; af < 4; ++af)                                              \
      tmax_ = fmaxf(tmax_, fmaxf(fmaxf(s4_[af][0], s4_[af][1]),                 \
                                 fmaxf(s4_[af][2], s4_[af][3])));               \
    tmax_ = fmaxf(tmax_, __shfl_xor(tmax_, 16, 64));                            \
    tmax_ = fmaxf(tmax_, __shfl_xor(tmax_, 32, 64));                            \
    if (!__all(tmax_ <= runm + 11.5416f)) {                                     \
      float newm_ = fmaxf(runm, tmax_);                                         \
      float corr_ = EXP2(runm - newm_);                                         \
      osum[0] *= corr_;                                                         \
      _Pragma("unroll")                                                         \
      for (int af = 0; af < 4; ++af) o[af] *= corr_;                            \
      runm = newm_;                                                             \
    }                                                                           \
    unsigned w_[4][2];                                                          \
    _Pragma("unroll")                                                           \
    for (int af = 0; af < 4; ++af) {                                            \
      _Pragma("unroll")                                                         \
      for (int r = 0; r < 4; ++r) s4_[af][r] = EXP2(s4_[af][r] - runm);         \
      asm("v_cvt_pk_bf16_f32 %0, %1, %2"                                        \
          : "=v"(w_[af][0]) : "v"(s4_[af][0]), "v"(s4_[af][1]));                \
      asm("v_cvt_pk_bf16_f32 %0, %1, %2"                                        \
          : "=v"(w_[af][1]) : "v"(s4_[af][2]), "v"(s4_[af][3]));                \
    }                                                                           \
    __builtin_amdgcn_s_setprio(1);                                              \
    _Pragma("unroll")                                                           \
    for (int kk = 0; kk < 2; ++kk) {                                            \
      unsigned a0_ = w_[2 * kk][0], a1_ = w_[2 * kk][1];                        \
      unsigned b0_ = w_[2 * kk + 1][0], b1_ = w_[2 * kk + 1][1];                \
      asm("v_permlane32_swap_b32 %0, %1" : "+v"(a0_), "+v"(b0_));               \
      asm("v_permlane16_swap_b32 %0, %1" : "+v"(a0_), "+v"(b0_));               \
      asm("v_permlane32_swap_b32 %0, %1" : "+v"(a1_), "+v"(b1_));               \
      asm("v_permlane16_swap_b32 %0, %1" : "+v"(a1_), "+v"(b1_));               \
      union { unsigned u[4]; bf16x8 v; } pu_;                                   \
      pu_.u[0] = a0_; pu_.u[1] = a1_; pu_.u[2] = b0_; pu_.u[3] = b1_;           \
      bf16x8 pf_ = pu_.v;                                                       \
      osum = __builtin_amdgcn_mfma_f32_16x16x32_bf16(ones, pf_, osum, 0, 0, 0); \
      _Pragma("unroll")                                                         \
      for (int af = 0; af < 4; ++af) {                                          \
        bf16x8 vf_ = *(const bf16x8*)&Vp[af * 32768 + kk * 32];                 \
        o[af] = __builtin_amdgcn_mfma_f32_16x16x32_bf16(vf_, pf_, o[af], 0, 0, 0); \
      }                                                                         \
    }                                                                           \
    __builtin_amdgcn_s_setprio(0);                                              \
    Kp += 4096;                                                                 \
    Vp += 64;                                                                   \
  } while (0)

  for (int it = 0; it < 16; ++it) {
    const int kt0 = 2 * it;
    TILE_BODY(mA, mB, kt0);       // consume mA, prefetch mB
    TILE_BODY(mB, mA, kt0 + 1);   // consume mB, prefetch mA
  }
#undef TILE_BODY

  float inv = 1.0f / osum[0];
  int tq = qt * 64 + wid * 16 + m;
  size_t obase = (((size_t)(b * 2048 + tq)) * 16 + h) * 64;
#pragma unroll
  for (int af = 0; af < 4; ++af) {
    ushort4v pk;
#pragma unroll
    for (int r = 0; r < 4; ++r) pk[r] = f2bf(o[af][r] * inv);
    *(ushort4v*)&O[obase + af * 16 + qg * 4] = pk;
  }
}

// ----------------------------------------------------------------
extern "C" void kernel_launch(void* const* d_in, const int* in_sizes, int n_in,
                              void* d_out, int out_size, void* d_ws, size_t ws_size,
                              hipStream_t stream) {
  const float* q  = (const float*)d_in[0];
  const float* k  = (const float*)d_in[1];
  const float* v  = (const float*)d_in[2];
  const int* mask = (const int*)d_in[3];
  const float* Wq = (const float*)d_in[4];
  const float* bq = (const float*)d_in[5];
  const float* Wk = (const float*)d_in[6];
  const float* bk = (const float*)d_in[7];
  const float* Wv = (const float*)d_in[8];
  const float* bv = (const float*)d_in[9];
  const float* Wo = (const float*)d_in[10];
  const float* bo = (const float*)d_in[11];
  float* out = (float*)d_out;

  const size_t NEED = (size_t)104 << 20;
  if (ws_size < NEED) return;

  char* ws = (char*)d_ws;
  ushort* WQb = (ushort*)(ws + ((size_t)0 << 20));
  ushort* WKb = (ushort*)(ws + ((size_t)2 << 20));
  ushort* WVb = (ushort*)(ws + ((size_t)4 << 20));
  ushort* WOb = (ushort*)(ws + ((size_t)6 << 20));
  ushort* qb  = (ushort*)(ws + ((size_t)8 << 20));
  ushort* kb  = (ushort*)(ws + ((size_t)24 << 20));
  ushort* vb  = (ushort*)(ws + ((size_t)40 << 20));
  ushort* Qs  = (ushort*)(ws + ((size_t)56 << 20));
  ushort* Ks  = (ushort*)(ws + ((size_t)72 << 20));
  ushort* Vts = (ushort*)(ws + ((size_t)88 << 20));
  ushort* Oat = qb;                 // dead after gemm3
  float* madd = (float*)d_out;      // scratch; overwritten by gemmF

  prep_all<<<dim3(1024, 8), dim3(256), 0, stream>>>(Wq, Wk, Wv, Wo, q, k, v, mask,
      (ushort4v*)WQb, (ushort4v*)WKb, (ushort4v*)WVb, (ushort4v*)WOb,
      (ushort4v*)qb, (ushort4v*)kb, (ushort4v*)vb, madd);

  gemm3<<<dim3(64, 8, 3), dim3(256), 0, stream>>>(qb, kb, vb, WQb, WKb, WVb,
      bq, bk, bv, Qs, Ks, Vts);

  attn<<<dim3(2048), dim3(256), 0, stream>>>(Qs, Ks, Vts, madd, Oat);

  gemmF<<<dim3(64, 8), dim3(256), 0, stream>>>(Oat, WOb, bo, out);
}

// Round 9
// 242.137 us; speedup vs baseline: 2.7053x; 2.7053x over previous
//
#include <hip/hip_runtime.h>
#include <hip/hip_bf16.h>

typedef __bf16 bf16x8 __attribute__((ext_vector_type(8)));
typedef float  f32x4  __attribute__((ext_vector_type(4)));
typedef unsigned short ushort;
typedef ushort ushort4v __attribute__((ext_vector_type(4)));

#if __has_builtin(__builtin_amdgcn_exp2f)
#define EXP2(x) __builtin_amdgcn_exp2f(x)
#else
#define EXP2(x) exp2f(x)
#endif

__device__ __forceinline__ ushort f2bf(float f) {
  union { float f; unsigned u; } v; v.f = f;
  unsigned r = v.u + 0x7FFFu + ((v.u >> 16) & 1u);
  return (ushort)(r >> 16);
}

typedef __attribute__((address_space(1))) const unsigned int as1_uint;
typedef __attribute__((address_space(3))) unsigned int as3_uint;
__device__ __forceinline__ void gll16(const void* g, void* l) {
  __builtin_amdgcn_global_load_lds((as1_uint*)g, (as3_uint*)l, 16, 0, 0);
}

// ------------------------------------------------ all casts + mask prep (merged)
// y 0-3: weight f32->bf16; y 4: mask; y 5-7: q/k/v f32->bf16.
// mask pre-scaled by log2(e): attn softmax runs in base-2 domain.
__global__ void prep_all(const float* __restrict__ Wq, const float* __restrict__ Wk,
                         const float* __restrict__ Wv, const float* __restrict__ Wo,
                         const float* __restrict__ q, const float* __restrict__ k,
                         const float* __restrict__ v, const int* __restrict__ mask,
                         ushort4v* __restrict__ wqb, ushort4v* __restrict__ wkb,
                         ushort4v* __restrict__ wvb, ushort4v* __restrict__ wob,
                         ushort4v* __restrict__ qb, ushort4v* __restrict__ kb,
                         ushort4v* __restrict__ vb, float* __restrict__ madd) {
  int y = blockIdx.y;
  if (y == 4) {
    int i = blockIdx.x * blockDim.x + threadIdx.x;
    if (i < 8192) {
      int mv = mask[i];
      madd[i] = (mv == 0) ? -9e15f * 1.44269504f : (float)mv * 1.44269504f;
    }
    return;
  }
  const float* s; ushort4v* d; int n4;
  if (y < 4) {
    s = (y == 0) ? Wq : (y == 1) ? Wk : (y == 2) ? Wv : Wo;
    d = (y == 0) ? wqb : (y == 1) ? wkb : (y == 2) ? wvb : wob;
    n4 = 1024 * 1024 / 4;
  } else {
    s = (y == 5) ? q : (y == 6) ? k : v;
    d = (y == 5) ? qb : (y == 6) ? kb : vb;
    n4 = 8192 * 1024 / 4;
  }
  const float4* s4p = (const float4*)s;
  for (int i = blockIdx.x * blockDim.x + threadIdx.x; i < n4; i += gridDim.x * blockDim.x) {
    float4 vv = s4p[i]; ushort4v o;
    o[0] = f2bf(vv.x); o[1] = f2bf(vv.y); o[2] = f2bf(vv.z); o[3] = f2bf(vv.w);
    d[i] = o;
  }
}

// ------------------------------------------------ GEMM core  C = A @ W^T + bias
// A [8192][1024] bf16, W [1024][1024] bf16. global_load_lds staging, pre-swizzled source.
// XCD-aware grid: blockIdx.x = M-tile (64), blockIdx.y = N-tile (8) so the 8
// N-blocks sharing one A-panel have linear bids m + 64n + 512z == m (mod 8):
// same XCD -> A-panel fetched once from HBM, 7x from that XCD's L2.
// mode 0: bf16 out in [B,H,T,D]; mode 1: f32 out [M][N]; mode 2: bf16 out transposed [B,H,D,T]
__device__ __forceinline__ void gemm_core(
    const ushort* __restrict__ A, const ushort* __restrict__ W,
    const float* __restrict__ bias, void* __restrict__ outp,
    float scale, int mode, ushort* smem)
{
  const int tid = threadIdx.x, lane = tid & 63, wid = tid >> 6;
  const int r0 = blockIdx.x * 128, c0 = blockIdx.y * 128;
  const int wr = (wid >> 1) * 64, wc = (wid & 1) * 64;
  const int K = 1024;
  ushort* sA = smem;
  ushort* sB = smem + 8192;

  f32x4 acc[4][4] = {};

  for (int kt = 0; kt < 16; ++kt) {
    const int k0 = kt * 64;
#pragma unroll
    for (int i = 0; i < 4; ++i) {
      int s = (wid * 4 + i) * 64 + lane;
      int row = s >> 3, sl = s & 7, gsl = sl ^ (row & 7);
      gll16(&A[(size_t)(r0 + row) * K + k0 + gsl * 8], &sA[(wid * 4 + i) * 512]);
      gll16(&W[(size_t)(c0 + row) * K + k0 + gsl * 8], &sB[(wid * 4 + i) * 512]);
    }
    __syncthreads();
#pragma unroll
    for (int kk = 0; kk < 2; ++kk) {
      bf16x8 af[4], bf[4];
#pragma unroll
      for (int mf = 0; mf < 4; ++mf) {
        int row = wr + mf * 16 + (lane & 15);
        int slot = (kk * 4 + (lane >> 4)) ^ (row & 7);
        af[mf] = *(const bf16x8*)&sA[row * 64 + slot * 8];
      }
#pragma unroll
      for (int nf = 0; nf < 4; ++nf) {
        int row = wc + nf * 16 + (lane & 15);
        int slot = (kk * 4 + (lane >> 4)) ^ (row & 7);
        bf[nf] = *(const bf16x8*)&sB[row * 64 + slot * 8];
      }
#pragma unroll
      for (int mf = 0; mf < 4; ++mf)
#pragma unroll
        for (int nf = 0; nf < 4; ++nf)
          acc[mf][nf] = __builtin_amdgcn_mfma_f32_16x16x32_bf16(af[mf], bf[nf], acc[mf][nf], 0, 0, 0);
    }
    __syncthreads();
  }

  if (mode == 2) {
    // transpose epilogue through LDS: sT[col][row ^ ((col&7)<<3)], 128x128
    ushort* sT = smem;
#pragma unroll
    for (int nf = 0; nf < 4; ++nf) {
      int col = wc + nf * 16 + (lane & 15);
      float bv = bias[c0 + col];
#pragma unroll
      for (int mf = 0; mf < 4; ++mf)
#pragma unroll
        for (int r = 0; r < 4; ++r) {
          int row = wr + mf * 16 + ((lane >> 4) * 4) + r;
          sT[col * 128 + (row ^ ((col & 7) << 3))] = f2bf(acc[mf][nf][r] + bv);
        }
    }
    __syncthreads();
    int bidx = r0 >> 11, tb = r0 & 2047;
#pragma unroll
    for (int it = 0; it < 8; ++it) {
      int colr = it * 16 + wid * 4 + (lane >> 4);
      int t0 = (lane & 15) * 8;
      int4 v = *(const int4*)&sT[colr * 128 + (t0 ^ ((colr & 7) << 3))];
      int colg = c0 + colr;
      int hh = colg >> 6, d = colg & 63;
      *(int4*)&((ushort*)outp)[((size_t)(bidx * 16 + hh) * 64 + d) * 2048 + tb + t0] = v;
    }
    return;
  }

#pragma unroll
  for (int nf = 0; nf < 4; ++nf) {
    int col = c0 + wc + nf * 16 + (lane & 15);
    float bv = bias[col];
#pragma unroll
    for (int mf = 0; mf < 4; ++mf) {
#pragma unroll
      for (int r = 0; r < 4; ++r) {
        int row = r0 + wr + mf * 16 + ((lane >> 4) * 4) + r;
        float v = (acc[mf][nf][r] + bv) * scale;
        if (mode == 0) {
          int b = row >> 11, t = row & 2047;
          int h = col >> 6, d = col & 63;
          ((ushort*)outp)[(((size_t)(b * 16 + h) * 2048 + t) << 6) + d] = f2bf(v);
        } else {
          ((float*)outp)[(size_t)row * 1024 + col] = v;
        }
      }
    }
  }
}

__global__ __launch_bounds__(256) void gemm3(
    const ushort* __restrict__ qb, const ushort* __restrict__ kb, const ushort* __restrict__ vb,
    const ushort* __restrict__ wq, const ushort* __restrict__ wk, const ushort* __restrict__ wv,
    const float* __restrict__ bq, const float* __restrict__ bk, const float* __restrict__ bv,
    ushort* __restrict__ Qs, ushort* __restrict__ Ks, ushort* __restrict__ Vts)
{
  __shared__ __align__(16) ushort smem[16384];
  int z = blockIdx.z;
  const ushort *A, *W; const float* bias; ushort* out; float scale; int mode;
  // Q scale carries log2(e): softmax computed as 2^x downstream.
  if (z == 0)      { A = qb; W = wq; bias = bq; out = Qs;  scale = 0.125f * 1.44269504f; mode = 0; }
  else if (z == 1) { A = kb; W = wk; bias = bk; out = Ks;  scale = 1.0f;   mode = 0; }
  else             { A = vb; W = wv; bias = bv; out = Vts; scale = 1.0f;   mode = 2; }
  gemm_core(A, W, bias, out, scale, mode, smem);
}

__global__ __launch_bounds__(256) void gemmF(
    const ushort* __restrict__ Oat, const ushort* __restrict__ wo,
    const float* __restrict__ bo, float* __restrict__ out)
{
  __shared__ __align__(16) ushort smem[16384];
  gemm_core(Oat, wo, bo, out, 1.0f, 1, smem);
}

// ------------------------------------------------ flash attention
// (R5-verified version, byte-identical.)
// Q,K: [B,H,2048,64] bf16 (Q pre-scaled by 0.125*log2e); Vt: [B,H,64,2048] bf16;
// O: [B,T,H,D] bf16. Base-2 softmax. Mask enters as the QK MFMA C-init (layout
// matches the C/D fragment). Clamp removed: provably inactive (|s| << 7e4).
// psum via ones-MFMA accumulator. K/V staged via global_load_lds with
// pre-swizzled source into ping-pong buffers; ONE barrier per tile.
__global__ __launch_bounds__(256) void attn(
    const ushort* __restrict__ Q, const ushort* __restrict__ Km,
    const ushort* __restrict__ Vt, const float* __restrict__ madd,
    ushort* __restrict__ O)
{
  __shared__ __align__(16) ushort sK[2][64 * 64];
  __shared__ __align__(16) ushort sV[2][64 * 64];

  const int tid = threadIdx.x, lane = tid & 63, wid = tid >> 6;
  const int bid = blockIdx.x;
  // XCD-aware mapping: all 32 q-tiles of one (b,h) land on one XCD's L2
  const int x = bid & 7, g = bid >> 3;
  const int pair = x * 8 + (g >> 5), qt = g & 31;
  const int b = pair >> 4, h = pair & 15;

  const size_t hb = (size_t)pair * (2048 * 64);
  const ushort* Qh = Q + hb + (size_t)qt * (64 * 64);
  const ushort* Kh = Km + hb;
  const ushort* Vh = Vt + hb;                 // [64][2048]
  const float* mb = madd + b * 2048;

  const int m = lane & 15, qg = lane >> 4;

  // stage one 64x64 tile (K and V halves) into buffer BSEL via global_load_lds;
  // source pre-swizzled so linear LDS == swizzled layout (read slot-XOR matches)
#define STAGE(BSEL, T) do {                                                     \
    const int n0g_ = (T) * 64;                                                  \
    _Pragma("unroll")                                                           \
    for (int i_ = 0; i_ < 2; ++i_) {                                            \
      int ch_ = wid * 2 + i_;                                                   \
      int s_ = ch_ * 64 + lane;                                                 \
      int row_ = s_ >> 3, sl_ = s_ & 7, gsl_ = sl_ ^ (row_ & 7);                \
      gll16(&Kh[(size_t)(n0g_ + row_) * 64 + gsl_ * 8], &sK[BSEL][ch_ * 512]);  \
      gll16(&Vh[(size_t)row_ * 2048 + n0g_ + gsl_ * 8], &sV[BSEL][ch_ * 512]);  \
    }                                                                           \
  } while (0)

  // Q fragments straight from global (16B contiguous per lane, one-time)
  bf16x8 qf[2];
#pragma unroll
  for (int kk = 0; kk < 2; ++kk)
    qf[kk] = *(const bf16x8*)&Qh[(size_t)(wid * 16 + m) * 64 + kk * 32 + qg * 8];

  // mask prefetch regs (tile 0)
  f32x4 mreg[4];
#pragma unroll
  for (int af = 0; af < 4; ++af)
    mreg[af] = *(const f32x4*)&mb[af * 16 + qg * 4];

  union { unsigned u[4]; bf16x8 v; } onesu;
  onesu.u[0] = onesu.u[1] = onesu.u[2] = onesu.u[3] = 0x3F803F80u;
  const bf16x8 ones = onesu.v;

  STAGE(0, 0);
  __syncthreads();   // drains gll16 vmcnt; buf0 ready

  float runm = -3.0e38f;
  f32x4 o[4] = {};
  f32x4 osum = {};

#define TILE_BODY(BK, BV, KT) do {                                              \
    f32x4 s4_[4];                                                               \
    _Pragma("unroll")                                                           \
    for (int af = 0; af < 4; ++af) s4_[af] = mreg[af];                          \
    if ((KT) < 31) {                                                            \
      const float* ms_ = mb + ((KT) + 1) * 64 + qg * 4;                         \
      _Pragma("unroll")                                                         \
      for (int af = 0; af < 4; ++af) mreg[af] = *(const f32x4*)&ms_[af * 16];   \
    }                                                                           \
    __builtin_amdgcn_s_setprio(1);                                              \
    _Pragma("unroll")                                                           \
    for (int af = 0; af < 4; ++af) {                                            \
      _Pragma("unroll")                                                         \
      for (int kk = 0; kk < 2; ++kk) {                                          \
        int krow_ = af * 16 + m;                                                \
        int slot_ = (kk * 4 + qg) ^ (krow_ & 7);                                \
        bf16x8 kf_ = *(const bf16x8*)&(BK)[krow_ * 64 + slot_ * 8];             \
        s4_[af] = __builtin_amdgcn_mfma_f32_16x16x32_bf16(kf_, qf[kk], s4_[af], 0, 0, 0); \
      }                                                                         \
    }                                                                           \
    __builtin_amdgcn_s_setprio(0);                                              \
    float tmax_ = fmaxf(fmaxf(s4_[0][0], s4_[0][1]), fmaxf(s4_[0][2], s4_[0][3])); \
    _Pragma("unroll")                                                           \
    for (int af = 1; af < 4; ++af)                                              \
      tmax_ = fmaxf(tmax_, fmaxf(fmaxf(s4_[af][0], s4_[af][1]),                 \
                                 fmaxf(s4_[af][2], s4_[af][3])));               \
    tmax_ = fmaxf(tmax_, __shfl_xor(tmax_, 16, 64));                            \
    tmax_ = fmaxf(tmax_, __shfl_xor(tmax_, 32, 64));                            \
    if (!__all(tmax_ <= runm + 11.5416f)) {                                     \
      float newm_ = fmaxf(runm, tmax_);                                         \
      float corr_ = EXP2(runm - newm_);                                         \
      osum[0] *= corr_;                                                         \
      _Pragma("unroll")                                                         \
      for (int af = 0; af < 4; ++af) o[af] *= corr_;                            \
      runm = newm_;                                                             \
    }                                                                           \
    unsigned w_[4][2];                                                          \
    _Pragma("unroll")                                                           \
    for (int af = 0; af < 4; ++af) {                                            \
      _Pragma("unroll")                                                         \
      for (int r = 0; r < 4; ++r) s4_[af][r] = EXP2(s4_[af][r] - runm);         \
      asm("v_cvt_pk_bf16_f32 %0, %1, %2"                                        \
          : "=v"(w_[af][0]) : "v"(s4_[af][0]), "v"(s4_[af][1]));                \
      asm("v_cvt_pk_bf16_f32 %0, %1, %2"                                        \
          : "=v"(w_[af][1]) : "v"(s4_[af][2]), "v"(s4_[af][3]));                \
    }                                                                           \
    __builtin_amdgcn_s_setprio(1);                                              \
    _Pragma("unroll")                                                           \
    for (int kk = 0; kk < 2; ++kk) {                                            \
      unsigned a0_ = w_[2 * kk][0], a1_ = w_[2 * kk][1];                        \
      unsigned b0_ = w_[2 * kk + 1][0], b1_ = w_[2 * kk + 1][1];                \
      asm("v_permlane32_swap_b32 %0, %1" : "+v"(a0_), "+v"(b0_));               \
      asm("v_permlane16_swap_b32 %0, %1" : "+v"(a0_), "+v"(b0_));               \
      asm("v_permlane32_swap_b32 %0, %1" : "+v"(a1_), "+v"(b1_));               \
      asm("v_permlane16_swap_b32 %0, %1" : "+v"(a1_), "+v"(b1_));               \
      union { unsigned u[4]; bf16x8 v; } pu_;                                   \
      pu_.u[0] = a0_; pu_.u[1] = a1_; pu_.u[2] = b0_; pu_.u[3] = b1_;           \
      bf16x8 pf_ = pu_.v;                                                       \
      osum = __builtin_amdgcn_mfma_f32_16x16x32_bf16(ones, pf_, osum, 0, 0, 0); \
      _Pragma("unroll")                                                         \
      for (int af = 0; af < 4; ++af) {                                          \
        int drow_ = af * 16 + m;                                                \
        int slot_ = (kk * 4 + qg) ^ (drow_ & 7);                                \
        bf16x8 vf_ = *(const bf16x8*)&(BV)[drow_ * 64 + slot_ * 8];             \
        o[af] = __builtin_amdgcn_mfma_f32_16x16x32_bf16(vf_, pf_, o[af], 0, 0, 0); \
      }                                                                         \
    }                                                                           \
    __builtin_amdgcn_s_setprio(0);                                              \
  } while (0)

  for (int it = 0; it < 16; ++it) {
    const int kt0 = 2 * it;
    // even: stage tile kt0+1 into buf1 (always valid), compute buf0
    STAGE(1, kt0 + 1);
    TILE_BODY(sK[0], sV[0], kt0);
    __syncthreads();   // drains staging; buf1 ready, buf0 free

    const int kt1 = kt0 + 1;
    if (kt1 < 31) STAGE(0, kt1 + 1);
    TILE_BODY(sK[1], sV[1], kt1);
    __syncthreads();
  }
#undef TILE_BODY
#undef STAGE

  float inv = 1.0f / osum[0];
  int tq = qt * 64 + wid * 16 + m;
  size_t obase = (((size_t)(b * 2048 + tq)) * 16 + h) * 64;
#pragma unroll
  for (int af = 0; af < 4; ++af) {
    ushort4v pk;
#pragma unroll
    for (int r = 0; r < 4; ++r) pk[r] = f2bf(o[af][r] * inv);
    *(ushort4v*)&O[obase + af * 16 + qg * 4] = pk;
  }
}

// ----------------------------------------------------------------
extern "C" void kernel_launch(void* const* d_in, const int* in_sizes, int n_in,
                              void* d_out, int out_size, void* d_ws, size_t ws_size,
                              hipStream_t stream) {
  const float* q  = (const float*)d_in[0];
  const float* k  = (const float*)d_in[1];
  const float* v  = (const float*)d_in[2];
  const int* mask = (const int*)d_in[3];
  const float* Wq = (const float*)d_in[4];
  const float* bq = (const float*)d_in[5];
  const float* Wk = (const float*)d_in[6];
  const float* bk = (const float*)d_in[7];
  const float* Wv = (const float*)d_in[8];
  const float* bv = (const float*)d_in[9];
  const float* Wo = (const float*)d_in[10];
  const float* bo = (const float*)d_in[11];
  float* out = (float*)d_out;

  const size_t NEED = (size_t)104 << 20;
  if (ws_size < NEED) return;

  char* ws = (char*)d_ws;
  ushort* WQb = (ushort*)(ws + ((size_t)0 << 20));
  ushort* WKb = (ushort*)(ws + ((size_t)2 << 20));
  ushort* WVb = (ushort*)(ws + ((size_t)4 << 20));
  ushort* WOb = (ushort*)(ws + ((size_t)6 << 20));
  ushort* qb  = (ushort*)(ws + ((size_t)8 << 20));
  ushort* kb  = (ushort*)(ws + ((size_t)24 << 20));
  ushort* vb  = (ushort*)(ws + ((size_t)40 << 20));
  ushort* Qs  = (ushort*)(ws + ((size_t)56 << 20));
  ushort* Ks  = (ushort*)(ws + ((size_t)72 << 20));
  ushort* Vts = (ushort*)(ws + ((size_t)88 << 20));
  ushort* Oat = qb;                 // dead after gemm3
  float* madd = (float*)d_out;      // scratch; overwritten by gemmF

  prep_all<<<dim3(1024, 8), dim3(256), 0, stream>>>(Wq, Wk, Wv, Wo, q, k, v, mask,
      (ushort4v*)WQb, (ushort4v*)WKb, (ushort4v*)WVb, (ushort4v*)WOb,
      (ushort4v*)qb, (ushort4v*)kb, (ushort4v*)vb, madd);

  gemm3<<<dim3(64, 8, 3), dim3(256), 0, stream>>>(qb, kb, vb, WQb, WKb, WVb,
      bq, bk, bv, Qs, Ks, Vts);

  attn<<<dim3(2048), dim3(256), 0, stream>>>(Qs, Ks, Vts, madd, Oat);

  gemmF<<<dim3(64, 8), dim3(256), 0, stream>>>(Oat, WOb, bo, out);
}

// Round 10
// 235.072 us; speedup vs baseline: 2.7866x; 1.0301x over previous
//
#include <hip/hip_runtime.h>
#include <hip/hip_bf16.h>

typedef __bf16 bf16x8 __attribute__((ext_vector_type(8)));
typedef float  f32x4  __attribute__((ext_vector_type(4)));
typedef unsigned short ushort;
typedef ushort ushort4v __attribute__((ext_vector_type(4)));

#if __has_builtin(__builtin_amdgcn_exp2f)
#define EXP2(x) __builtin_amdgcn_exp2f(x)
#else
#define EXP2(x) exp2f(x)
#endif

__device__ __forceinline__ ushort f2bf(float f) {
  union { float f; unsigned u; } v; v.f = f;
  unsigned r = v.u + 0x7FFFu + ((v.u >> 16) & 1u);
  return (ushort)(r >> 16);
}

typedef __attribute__((address_space(1))) const unsigned int as1_uint;
typedef __attribute__((address_space(3))) unsigned int as3_uint;
__device__ __forceinline__ void gll16(const void* g, void* l) {
  __builtin_amdgcn_global_load_lds((as1_uint*)g, (as3_uint*)l, 16, 0, 0);
}

// ------------------------------------------------ all casts + mask prep (merged)
// y 0-3: weight f32->bf16; y 4: mask; y 5-7: q/k/v f32->bf16.
// mask pre-scaled by log2(e): attn softmax runs in base-2 domain.
__global__ void prep_all(const float* __restrict__ Wq, const float* __restrict__ Wk,
                         const float* __restrict__ Wv, const float* __restrict__ Wo,
                         const float* __restrict__ q, const float* __restrict__ k,
                         const float* __restrict__ v, const int* __restrict__ mask,
                         ushort4v* __restrict__ wqb, ushort4v* __restrict__ wkb,
                         ushort4v* __restrict__ wvb, ushort4v* __restrict__ wob,
                         ushort4v* __restrict__ qb, ushort4v* __restrict__ kb,
                         ushort4v* __restrict__ vb, float* __restrict__ madd) {
  int y = blockIdx.y;
  if (y == 4) {
    int i = blockIdx.x * blockDim.x + threadIdx.x;
    if (i < 8192) {
      int mv = mask[i];
      madd[i] = (mv == 0) ? -9e15f * 1.44269504f : (float)mv * 1.44269504f;
    }
    return;
  }
  const float* s; ushort4v* d; int n4;
  if (y < 4) {
    s = (y == 0) ? Wq : (y == 1) ? Wk : (y == 2) ? Wv : Wo;
    d = (y == 0) ? wqb : (y == 1) ? wkb : (y == 2) ? wvb : wob;
    n4 = 1024 * 1024 / 4;
  } else {
    s = (y == 5) ? q : (y == 6) ? k : v;
    d = (y == 5) ? qb : (y == 6) ? kb : vb;
    n4 = 8192 * 1024 / 4;
  }
  const float4* s4p = (const float4*)s;
  for (int i = blockIdx.x * blockDim.x + threadIdx.x; i < n4; i += gridDim.x * blockDim.x) {
    float4 vv = s4p[i]; ushort4v o;
    o[0] = f2bf(vv.x); o[1] = f2bf(vv.y); o[2] = f2bf(vv.z); o[3] = f2bf(vv.w);
    d[i] = o;
  }
}

// ------------------------------------------------ GEMM core  C = A @ W^T + bias
// A [8192][1024] bf16, W [1024][1024] bf16. global_load_lds staging, pre-swizzled source.
// XCD-aware grid: blockIdx.x = M-tile (64), blockIdx.y = N-tile (8) so the 8
// N-blocks sharing one A-panel have linear bids m + 64n + 512z == m (mod 8):
// same XCD -> A-panel fetched once from HBM, 7x from that XCD's L2.
// mode 0: bf16 out in [B,H,T,D] (LDS-vectorized epilogue, 16B stores);
// mode 1: f32 out [M][N]; mode 2: bf16 out transposed [B,H,D,T]
__device__ __forceinline__ void gemm_core(
    const ushort* __restrict__ A, const ushort* __restrict__ W,
    const float* __restrict__ bias, void* __restrict__ outp,
    float scale, int mode, ushort* smem)
{
  const int tid = threadIdx.x, lane = tid & 63, wid = tid >> 6;
  const int r0 = blockIdx.x * 128, c0 = blockIdx.y * 128;
  const int wr = (wid >> 1) * 64, wc = (wid & 1) * 64;
  const int K = 1024;
  ushort* sA = smem;
  ushort* sB = smem + 8192;

  f32x4 acc[4][4] = {};

  for (int kt = 0; kt < 16; ++kt) {
    const int k0 = kt * 64;
#pragma unroll
    for (int i = 0; i < 4; ++i) {
      int s = (wid * 4 + i) * 64 + lane;
      int row = s >> 3, sl = s & 7, gsl = sl ^ (row & 7);
      gll16(&A[(size_t)(r0 + row) * K + k0 + gsl * 8], &sA[(wid * 4 + i) * 512]);
      gll16(&W[(size_t)(c0 + row) * K + k0 + gsl * 8], &sB[(wid * 4 + i) * 512]);
    }
    __syncthreads();
#pragma unroll
    for (int kk = 0; kk < 2; ++kk) {
      bf16x8 af[4], bf[4];
#pragma unroll
      for (int mf = 0; mf < 4; ++mf) {
        int row = wr + mf * 16 + (lane & 15);
        int slot = (kk * 4 + (lane >> 4)) ^ (row & 7);
        af[mf] = *(const bf16x8*)&sA[row * 64 + slot * 8];
      }
#pragma unroll
      for (int nf = 0; nf < 4; ++nf) {
        int row = wc + nf * 16 + (lane & 15);
        int slot = (kk * 4 + (lane >> 4)) ^ (row & 7);
        bf[nf] = *(const bf16x8*)&sB[row * 64 + slot * 8];
      }
#pragma unroll
      for (int mf = 0; mf < 4; ++mf)
#pragma unroll
        for (int nf = 0; nf < 4; ++nf)
          acc[mf][nf] = __builtin_amdgcn_mfma_f32_16x16x32_bf16(af[mf], bf[nf], acc[mf][nf], 0, 0, 0);
    }
    __syncthreads();
  }

  if (mode == 2) {
    // transpose epilogue through LDS: sT[col][row ^ ((col&7)<<3)], 128x128
    ushort* sT = smem;
#pragma unroll
    for (int nf = 0; nf < 4; ++nf) {
      int col = wc + nf * 16 + (lane & 15);
      float bv = bias[c0 + col];
#pragma unroll
      for (int mf = 0; mf < 4; ++mf)
#pragma unroll
        for (int r = 0; r < 4; ++r) {
          int row = wr + mf * 16 + ((lane >> 4) * 4) + r;
          sT[col * 128 + (row ^ ((col & 7) << 3))] = f2bf(acc[mf][nf][r] + bv);
        }
    }
    __syncthreads();
    int bidx = r0 >> 11, tb = r0 & 2047;
#pragma unroll
    for (int it = 0; it < 8; ++it) {
      int colr = it * 16 + wid * 4 + (lane >> 4);
      int t0 = (lane & 15) * 8;
      int4 v = *(const int4*)&sT[colr * 128 + (t0 ^ ((colr & 7) << 3))];
      int colg = c0 + colr;
      int hh = colg >> 6, d = colg & 63;
      *(int4*)&((ushort*)outp)[((size_t)(bidx * 16 + hh) * 64 + d) * 2048 + tb + t0] = v;
    }
    return;
  }

  if (mode == 0) {
    // vectorized epilogue through LDS (same swizzle family as mode 2):
    // stage sT[row][col ^ ((row&7)<<3)], then 16B coalesced stores.
    // Values and destination addresses identical to the old scalar path.
    ushort* sT = smem;
#pragma unroll
    for (int nf = 0; nf < 4; ++nf) {
      int col = wc + nf * 16 + (lane & 15);
      float bv = bias[c0 + col];
#pragma unroll
      for (int mf = 0; mf < 4; ++mf)
#pragma unroll
        for (int r = 0; r < 4; ++r) {
          int row = wr + mf * 16 + ((lane >> 4) * 4) + r;
          sT[row * 128 + (col ^ ((row & 7) << 3))] =
              f2bf((acc[mf][nf][r] + bv) * scale);
        }
    }
    __syncthreads();
#pragma unroll
    for (int it = 0; it < 8; ++it) {
      int rowr = it * 16 + wid * 4 + (lane >> 4);       // 0..127
      int c8 = (lane & 15) * 8;                          // 8-aligned col base
      int4 v = *(const int4*)&sT[rowr * 128 + (c8 ^ ((rowr & 7) << 3))];
      int grow = r0 + rowr, gb = grow >> 11, t = grow & 2047;
      int colg = c0 + c8, hh = colg >> 6, d = colg & 63;
      *(int4*)&((ushort*)outp)[(((size_t)(gb * 16 + hh) * 2048 + t) << 6) + d] = v;
    }
    return;
  }

#pragma unroll
  for (int nf = 0; nf < 4; ++nf) {
    int col = c0 + wc + nf * 16 + (lane & 15);
    float bv = bias[col];
#pragma unroll
    for (int mf = 0; mf < 4; ++mf) {
#pragma unroll
      for (int r = 0; r < 4; ++r) {
        int row = r0 + wr + mf * 16 + ((lane >> 4) * 4) + r;
        float v = (acc[mf][nf][r] + bv) * scale;
        ((float*)outp)[(size_t)row * 1024 + col] = v;
      }
    }
  }
}

__global__ __launch_bounds__(256) void gemm3(
    const ushort* __restrict__ qb, const ushort* __restrict__ kb, const ushort* __restrict__ vb,
    const ushort* __restrict__ wq, const ushort* __restrict__ wk, const ushort* __restrict__ wv,
    const float* __restrict__ bq, const float* __restrict__ bk, const float* __restrict__ bv,
    ushort* __restrict__ Qs, ushort* __restrict__ Ks, ushort* __restrict__ Vts)
{
  __shared__ __align__(16) ushort smem[16384];
  int z = blockIdx.z;
  const ushort *A, *W; const float* bias; ushort* out; float scale; int mode;
  // Q scale carries log2(e): softmax computed as 2^x downstream.
  if (z == 0)      { A = qb; W = wq; bias = bq; out = Qs;  scale = 0.125f * 1.44269504f; mode = 0; }
  else if (z == 1) { A = kb; W = wk; bias = bk; out = Ks;  scale = 1.0f;   mode = 0; }
  else             { A = vb; W = wv; bias = bv; out = Vts; scale = 1.0f;   mode = 2; }
  gemm_core(A, W, bias, out, scale, mode, smem);
}

__global__ __launch_bounds__(256) void gemmF(
    const ushort* __restrict__ Oat, const ushort* __restrict__ wo,
    const float* __restrict__ bo, float* __restrict__ out)
{
  __shared__ __align__(16) ushort smem[16384];
  gemm_core(Oat, wo, bo, out, 1.0f, 1, smem);
}

// ------------------------------------------------ flash attention
// (R5-verified skeleton; tmax tree reassociated into fmax-triples so clang
// fuses v_max3_f32 — bit-identical result, ~6 fewer VALU ops per tile.)
// Q,K: [B,H,2048,64] bf16 (Q pre-scaled by 0.125*log2e); Vt: [B,H,64,2048] bf16;
// O: [B,T,H,D] bf16. Base-2 softmax. Mask enters as the QK MFMA C-init (layout
// matches the C/D fragment). Clamp removed: provably inactive (|s| << 7e4).
// psum via ones-MFMA accumulator. K/V staged via global_load_lds with
// pre-swizzled source into ping-pong buffers; ONE barrier per tile.
__global__ __launch_bounds__(256) void attn(
    const ushort* __restrict__ Q, const ushort* __restrict__ Km,
    const ushort* __restrict__ Vt, const float* __restrict__ madd,
    ushort* __restrict__ O)
{
  __shared__ __align__(16) ushort sK[2][64 * 64];
  __shared__ __align__(16) ushort sV[2][64 * 64];

  const int tid = threadIdx.x, lane = tid & 63, wid = tid >> 6;
  const int bid = blockIdx.x;
  // XCD-aware mapping: all 32 q-tiles of one (b,h) land on one XCD's L2
  const int x = bid & 7, g = bid >> 3;
  const int pair = x * 8 + (g >> 5), qt = g & 31;
  const int b = pair >> 4, h = pair & 15;

  const size_t hb = (size_t)pair * (2048 * 64);
  const ushort* Qh = Q + hb + (size_t)qt * (64 * 64);
  const ushort* Kh = Km + hb;
  const ushort* Vh = Vt + hb;                 // [64][2048]
  const float* mb = madd + b * 2048;

  const int m = lane & 15, qg = lane >> 4;

  // stage one 64x64 tile (K and V halves) into buffer BSEL via global_load_lds;
  // source pre-swizzled so linear LDS == swizzled layout (read slot-XOR matches)
#define STAGE(BSEL, T) do {                                                     \
    const int n0g_ = (T) * 64;                                                  \
    _Pragma("unroll")                                                           \
    for (int i_ = 0; i_ < 2; ++i_) {                                            \
      int ch_ = wid * 2 + i_;                                                   \
      int s_ = ch_ * 64 + lane;                                                 \
      int row_ = s_ >> 3, sl_ = s_ & 7, gsl_ = sl_ ^ (row_ & 7);                \
      gll16(&Kh[(size_t)(n0g_ + row_) * 64 + gsl_ * 8], &sK[BSEL][ch_ * 512]);  \
      gll16(&Vh[(size_t)row_ * 2048 + n0g_ + gsl_ * 8], &sV[BSEL][ch_ * 512]);  \
    }                                                                           \
  } while (0)

  // Q fragments straight from global (16B contiguous per lane, one-time)
  bf16x8 qf[2];
#pragma unroll
  for (int kk = 0; kk < 2; ++kk)
    qf[kk] = *(const bf16x8*)&Qh[(size_t)(wid * 16 + m) * 64 + kk * 32 + qg * 8];

  // mask prefetch regs (tile 0)
  f32x4 mreg[4];
#pragma unroll
  for (int af = 0; af < 4; ++af)
    mreg[af] = *(const f32x4*)&mb[af * 16 + qg * 4];

  union { unsigned u[4]; bf16x8 v; } onesu;
  onesu.u[0] = onesu.u[1] = onesu.u[2] = onesu.u[3] = 0x3F803F80u;
  const bf16x8 ones = onesu.v;

  STAGE(0, 0);
  __syncthreads();   // drains gll16 vmcnt; buf0 ready

  float runm = -3.0e38f;
  f32x4 o[4] = {};
  f32x4 osum = {};

#define TILE_BODY(BK, BV, KT) do {                                              \
    f32x4 s4_[4];                                                               \
    _Pragma("unroll")                                                           \
    for (int af = 0; af < 4; ++af) s4_[af] = mreg[af];                          \
    if ((KT) < 31) {                                                            \
      const float* ms_ = mb + ((KT) + 1) * 64 + qg * 4;                         \
      _Pragma("unroll")                                                         \
      for (int af = 0; af < 4; ++af) mreg[af] = *(const f32x4*)&ms_[af * 16];   \
    }                                                                           \
    __builtin_amdgcn_s_setprio(1);                                              \
    _Pragma("unroll")                                                           \
    for (int af = 0; af < 4; ++af) {                                            \
      _Pragma("unroll")                                                         \
      for (int kk = 0; kk < 2; ++kk) {                                          \
        int krow_ = af * 16 + m;                                                \
        int slot_ = (kk * 4 + qg) ^ (krow_ & 7);                                \
        bf16x8 kf_ = *(const bf16x8*)&(BK)[krow_ * 64 + slot_ * 8];             \
        s4_[af] = __builtin_amdgcn_mfma_f32_16x16x32_bf16(kf_, qf[kk], s4_[af], 0, 0, 0); \
      }                                                                         \
    }                                                                           \
    __builtin_amdgcn_s_setprio(0);                                              \
    /* max3-friendly triples: bit-identical to the flat fmax tree */            \
    float p0_ = fmaxf(fmaxf(s4_[0][0], s4_[0][1]), s4_[0][2]);                  \
    float p1_ = fmaxf(fmaxf(s4_[0][3], s4_[1][0]), s4_[1][1]);                  \
    float p2_ = fmaxf(fmaxf(s4_[1][2], s4_[1][3]), s4_[2][0]);                  \
    float p3_ = fmaxf(fmaxf(s4_[2][1], s4_[2][2]), s4_[2][3]);                  \
    float p4_ = fmaxf(fmaxf(s4_[3][0], s4_[3][1]), s4_[3][2]);                  \
    float tmax_ = fmaxf(fmaxf(fmaxf(p0_, p1_), fmaxf(p2_, p3_)),                \
                        fmaxf(p4_, s4_[3][3]));                                 \
    tmax_ = fmaxf(tmax_, __shfl_xor(tmax_, 16, 64));                            \
    tmax_ = fmaxf(tmax_, __shfl_xor(tmax_, 32, 64));                            \
    if (!__all(tmax_ <= runm + 11.5416f)) {                                     \
      float newm_ = fmaxf(runm, tmax_);                                         \
      float corr_ = EXP2(runm - newm_);                                         \
      osum[0] *= corr_;                                                         \
      _Pragma("unroll")                                                         \
      for (int af = 0; af < 4; ++af) o[af] *= corr_;                            \
      runm = newm_;                                                             \
    }                                                                           \
    unsigned w_[4][2];                                                          \
    _Pragma("unroll")                                                           \
    for (int af = 0; af < 4; ++af) {                                            \
      _Pragma("unroll")                                                         \
      for (int r = 0; r < 4; ++r) s4_[af][r] = EXP2(s4_[af][r] - runm);         \
      asm("v_cvt_pk_bf16_f32 %0, %1, %2"                                        \
          : "=v"(w_[af][0]) : "v"(s4_[af][0]), "v"(s4_[af][1]));                \
      asm("v_cvt_pk_bf16_f32 %0, %1, %2"                                        \
          : "=v"(w_[af][1]) : "v"(s4_[af][2]), "v"(s4_[af][3]));                \
    }                                                                           \
    __builtin_amdgcn_s_setprio(1);                                              \
    _Pragma("unroll")                                                           \
    for (int kk = 0; kk < 2; ++kk) {                                            \
      unsigned a0_ = w_[2 * kk][0], a1_ = w_[2 * kk][1];                        \
      unsigned b0_ = w_[2 * kk + 1][0], b1_ = w_[2 * kk + 1][1];                \
      asm("v_permlane32_swap_b32 %0, %1" : "+v"(a0_), "+v"(b0_));               \
      asm("v_permlane16_swap_b32 %0, %1" : "+v"(a0_), "+v"(b0_));               \
      asm("v_permlane32_swap_b32 %0, %1" : "+v"(a1_), "+v"(b1_));               \
      asm("v_permlane16_swap_b32 %0, %1" : "+v"(a1_), "+v"(b1_));               \
      union { unsigned u[4]; bf16x8 v; } pu_;                                   \
      pu_.u[0] = a0_; pu_.u[1] = a1_; pu_.u[2] = b0_; pu_.u[3] = b1_;           \
      bf16x8 pf_ = pu_.v;                                                       \
      osum = __builtin_amdgcn_mfma_f32_16x16x32_bf16(ones, pf_, osum, 0, 0, 0); \
      _Pragma("unroll")                                                         \
      for (int af = 0; af < 4; ++af) {                                          \
        int drow_ = af * 16 + m;                                                \
        int slot_ = (kk * 4 + qg) ^ (drow_ & 7);                                \
        bf16x8 vf_ = *(const bf16x8*)&(BV)[drow_ * 64 + slot_ * 8];             \
        o[af] = __builtin_amdgcn_mfma_f32_16x16x32_bf16(vf_, pf_, o[af], 0, 0, 0); \
      }                                                                         \
    }                                                                           \
    __builtin_amdgcn_s_setprio(0);                                              \
  } while (0)

  for (int it = 0; it < 16; ++it) {
    const int kt0 = 2 * it;
    // even: stage tile kt0+1 into buf1 (always valid), compute buf0
    STAGE(1, kt0 + 1);
    TILE_BODY(sK[0], sV[0], kt0);
    __syncthreads();   // drains staging; buf1 ready, buf0 free

    const int kt1 = kt0 + 1;
    if (kt1 < 31) STAGE(0, kt1 + 1);
    TILE_BODY(sK[1], sV[1], kt1);
    __syncthreads();
  }
#undef TILE_BODY
#undef STAGE

  float inv = 1.0f / osum[0];
  int tq = qt * 64 + wid * 16 + m;
  size_t obase = (((size_t)(b * 2048 + tq)) * 16 + h) * 64;
#pragma unroll
  for (int af = 0; af < 4; ++af) {
    ushort4v pk;
#pragma unroll
    for (int r = 0; r < 4; ++r) pk[r] = f2bf(o[af][r] * inv);
    *(ushort4v*)&O[obase + af * 16 + qg * 4] = pk;
  }
}

// ----------------------------------------------------------------
extern "C" void kernel_launch(void* const* d_in, const int* in_sizes, int n_in,
                              void* d_out, int out_size, void* d_ws, size_t ws_size,
                              hipStream_t stream) {
  const float* q  = (const float*)d_in[0];
  const float* k  = (const float*)d_in[1];
  const float* v  = (const float*)d_in[2];
  const int* mask = (const int*)d_in[3];
  const float* Wq = (const float*)d_in[4];
  const float* bq = (const float*)d_in[5];
  const float* Wk = (const float*)d_in[6];
  const float* bk = (const float*)d_in[7];
  const float* Wv = (const float*)d_in[8];
  const float* bv = (const float*)d_in[9];
  const float* Wo = (const float*)d_in[10];
  const float* bo = (const float*)d_in[11];
  float* out = (float*)d_out;

  const size_t NEED = (size_t)104 << 20;
  if (ws_size < NEED) return;

  char* ws = (char*)d_ws;
  ushort* WQb = (ushort*)(ws + ((size_t)0 << 20));
  ushort* WKb = (ushort*)(ws + ((size_t)2 << 20));
  ushort* WVb = (ushort*)(ws + ((size_t)4 << 20));
  ushort* WOb = (ushort*)(ws + ((size_t)6 << 20));
  ushort* qb  = (ushort*)(ws + ((size_t)8 << 20));
  ushort* kb  = (ushort*)(ws + ((size_t)24 << 20));
  ushort* vb  = (ushort*)(ws + ((size_t)40 << 20));
  ushort* Qs  = (ushort*)(ws + ((size_t)56 << 20));
  ushort* Ks  = (ushort*)(ws + ((size_t)72 << 20));
  ushort* Vts = (ushort*)(ws + ((size_t)88 << 20));
  ushort* Oat = qb;                 // dead after gemm3
  float* madd = (float*)d_out;      // scratch; overwritten by gemmF

  prep_all<<<dim3(1024, 8), dim3(256), 0, stream>>>(Wq, Wk, Wv, Wo, q, k, v, mask,
      (ushort4v*)WQb, (ushort4v*)WKb, (ushort4v*)WVb, (ushort4v*)WOb,
      (ushort4v*)qb, (ushort4v*)kb, (ushort4v*)vb, madd);

  gemm3<<<dim3(64, 8, 3), dim3(256), 0, stream>>>(qb, kb, vb, WQb, WKb, WVb,
      bq, bk, bv, Qs, Ks, Vts);

  attn<<<dim3(2048), dim3(256), 0, stream>>>(Qs, Ks, Vts, madd, Oat);

  gemmF<<<dim3(64, 8), dim3(256), 0, stream>>>(Oat, WOb, bo, out);
}